// Round 2
// baseline (330.494 us; speedup 1.0000x reference)
//
#include <hip/hip_runtime.h>

#define EPSV 1e-5f
constexpr int Bb = 4, Cc = 64, Nn = 40960, Kk = 16, Dd = 128;
constexpr int G = 4;                       // point-tiles per block in fused_main
constexpr int TPB = Nn / 16;               // tiles per batch = 2560

typedef float f32x4 __attribute__((ext_vector_type(4)));
typedef __bf16 bf16x8 __attribute__((ext_vector_type(8)));
typedef unsigned short us8 __attribute__((ext_vector_type(8)));

__device__ inline unsigned short f2bf(float x) {
    unsigned u = __builtin_bit_cast(unsigned, x);
    u += 0x7FFFu + ((u >> 16) & 1u);   // RNE
    return (unsigned short)(u >> 16);
}

// ---------------------------------------------------------------------------
// Pass 1: feature (B,C,N) fp32 -> ft (B,N,C) bf16, LDS-tiled 64x64.
// Reads: 256 B contiguous per wave-instr. Writes: fully contiguous 32 B/thread.
// LDS fp32 tile with +1 pad => 2-way (free) bank aliasing both phases.
__global__ __launch_bounds__(256) void transpose_cvt(const float* __restrict__ f,
                                                     unsigned short* __restrict__ ft) {
    __shared__ float s[64 * 65];
    const int tid = threadIdx.x, w = tid >> 6, l = tid & 63;
    const int b = blockIdx.x / 640;
    const int n0 = (blockIdx.x % 640) * 64;

    const float* src = f + ((size_t)b * Cc + w * 16) * Nn + n0 + l;
#pragma unroll
    for (int i = 0; i < 16; ++i) s[(w * 16 + i) * 65 + l] = src[(size_t)i * Nn];
    __syncthreads();

    const int n = tid >> 2, cg = tid & 3;
    us8 o0, o1;
#pragma unroll
    for (int j = 0; j < 8; ++j) o0[j] = f2bf(s[(cg * 16 + j) * 65 + n]);
#pragma unroll
    for (int j = 0; j < 8; ++j) o1[j] = f2bf(s[(cg * 16 + 8 + j) * 65 + n]);
    unsigned short* dst = ft + ((size_t)b * Nn + n0 + n) * 64 + cg * 16;
    *(us8*)dst = o0;
    *(us8*)(dst + 8) = o1;
}

// ---------------------------------------------------------------------------
// Prep: fold BN scale into bf16 weights, precompute shifts.
__global__ __launch_bounds__(256) void prep_weights(
    const float* __restrict__ w1, const float* __restrict__ g1, const float* __restrict__ b1,
    const float* __restrict__ m1, const float* __restrict__ v1,
    const float* __restrict__ w2, const float* __restrict__ g2, const float* __restrict__ b2,
    const float* __restrict__ m2, const float* __restrict__ v2,
    const float* __restrict__ w3, const float* __restrict__ g3, const float* __restrict__ b3,
    const float* __restrict__ m3, const float* __restrict__ v3,
    unsigned short* __restrict__ w1s, unsigned short* __restrict__ w2s, unsigned short* __restrict__ w3s,
    float* __restrict__ sh1, float* __restrict__ sh2, float* __restrict__ sh3) {
    const int e = blockIdx.x * 256 + threadIdx.x;
    if (e < 4096) {
        const int o = e >> 6;
        const float sc = g1[o] * rsqrtf(v1[o] + EPSV);
        w1s[e] = f2bf(w1[e] * sc);
    } else if (e < 12288) {
        const int i = e - 4096, o = i >> 6;
        const float sc = g2[o] * rsqrtf(v2[o] + EPSV);
        w2s[i] = f2bf(w2[i] * sc);
    } else if (e < 20480) {
        const int i = e - 12288, o = i >> 6;
        const float sc = g3[o] * rsqrtf(v3[o] + EPSV);
        w3s[i] = f2bf(w3[i] * sc);
    }
    if (e < 64) sh1[e] = b1[e] - m1[e] * (g1[e] * rsqrtf(v1[e] + EPSV));
    else if (e < 192) { const int d = e - 64;  sh2[d] = b2[d] - m2[d] * (g2[d] * rsqrtf(v2[d] + EPSV)); }
    else if (e < 320) { const int d = e - 192; sh3[d] = b3[d] - m3[d] * (g3[d] * rsqrtf(v3[d] + EPSV)); }
}

// ---------------------------------------------------------------------------
// Main fused kernel: G point-tiles (16 points each) per block, 256 threads.
// Register-prefetch pipeline: tile g+1's gather rides under tile g's compute.
__global__ __launch_bounds__(256) void fused_main(
    const unsigned short* __restrict__ ft, const int* __restrict__ idx,
    const unsigned short* __restrict__ w1s, const unsigned short* __restrict__ w2s,
    const unsigned short* __restrict__ w3s,
    const float* __restrict__ sh1, const float* __restrict__ sh2, const float* __restrict__ sh3,
    float* __restrict__ out) {
    __shared__ __attribute__((aligned(16))) unsigned short s_gath[256 * 72]; // 36 KB; s_out aliases
    __shared__ __attribute__((aligned(16))) unsigned short s_h1[16 * 72];
    __shared__ __attribute__((aligned(16))) unsigned short s_fo[16 * 72];
    float* s_out = (float*)s_gath;   // 16*132 floats = 8.25 KB, reused after GEMM1 reads done

    const int tid  = threadIdx.x;
    const int wave = tid >> 6;
    const int lane = tid & 63;
    const int c15  = lane & 15;
    const int q    = lane >> 4;
    const int sub  = lane & 7;
    const int rloc = lane >> 3;             // 0..7: row-within-8 handled by this lane

    const int t0  = blockIdx.x * G;
    const int b   = t0 / TPB;               // G | TPB, so whole block is one batch
    const int nb0 = (t0 - b * TPB) * 16;    // first point of tile 0

    // ---- register-resident weight fragments (pre-scaled bf16) ----
    const int o1i = wave * 16 + c15;
    const float sh1v = sh1[o1i];
    bf16x8 bw1[2];
#pragma unroll
    for (int ks = 0; ks < 2; ++ks)
        bw1[ks] = __builtin_bit_cast(bf16x8, *(const uint4*)(w1s + o1i * 64 + ks * 32 + q * 8));

    float sh2v[2], sh3v[2];
    bf16x8 bw2[2][2], bw3[2][2];
#pragma unroll
    for (int nt = 0; nt < 2; ++nt) {
        const int d = wave * 32 + nt * 16 + c15;
        sh2v[nt] = sh2[d];
        sh3v[nt] = sh3[d];
#pragma unroll
        for (int ks = 0; ks < 2; ++ks) {
            bw2[nt][ks] = __builtin_bit_cast(bf16x8, *(const uint4*)(w2s + d * 64 + ks * 32 + q * 8));
            bw3[nt][ks] = __builtin_bit_cast(bf16x8, *(const uint4*)(w3s + d * 64 + ks * 32 + q * 8));
        }
    }

    // ---- idx for all G tiles upfront (coalesced, 1 int/thread/tile) ----
    const size_t ibase = ((size_t)b * Nn + nb0) * Kk;
    int idxg[G];
#pragma unroll
    for (int g = 0; g < G; ++g) idxg[g] = idx[ibase + g * 256 + tid];

    const unsigned short* ftb = ft + (size_t)b * Nn * 64;

    uint4 preg[8];   // gather prefetch: rows 64*wave .. 64*wave+63, 16 B chunk `sub`
    uint4 freg;      // own-feature prefetch (threads < 128)

    // prefetch tile 0
#pragma unroll
    for (int i = 0; i < 8; ++i) {
        const int nb = __shfl(idxg[0], i * 8 + rloc, 64);
        preg[i] = *(const uint4*)(ftb + (size_t)nb * 64 + sub * 8);
    }
    if (tid < 128) freg = *(const uint4*)(ftb + (size_t)(nb0 + (tid >> 3)) * 64 + (tid & 7) * 8);

#pragma unroll
    for (int g = 0; g < G; ++g) {
        const int n0 = nb0 + g * 16;
        __syncthreads();                                   // (a) prev s_out reads done
        // commit prefetched registers to LDS
#pragma unroll
        for (int i = 0; i < 8; ++i)
            *(uint4*)(s_gath + (64 * wave + i * 8 + rloc) * 72 + sub * 8) = preg[i];
        if (tid < 128)
            *(uint4*)(s_fo + (tid >> 3) * 72 + (tid & 7) * 8) = freg;
        __syncthreads();                                   // (b)

        // launch next tile's gather (overlaps all compute below)
        if (g + 1 < G) {
#pragma unroll
            for (int i = 0; i < 8; ++i) {
                const int nb = __shfl(idxg[g + 1], i * 8 + rloc, 64);
                preg[i] = *(const uint4*)(ftb + (size_t)nb * 64 + sub * 8);
            }
            if (tid < 128)
                freg = *(const uint4*)(ftb + (size_t)(n0 + 16 + (tid >> 3)) * 64 + (tid & 7) * 8);
        }

        // ---- GEMM1: per point, 16 nbrs x 64ch -> 16ch/wave; BN+ReLU; K-sum ----
#pragma unroll
        for (int mt = 0; mt < 16; ++mt) {
            const unsigned short* row = s_gath + (mt * 16 + c15) * 72;
            const bf16x8 a0 = __builtin_bit_cast(bf16x8, *(const uint4*)(row + q * 8));
            const bf16x8 a1 = __builtin_bit_cast(bf16x8, *(const uint4*)(row + 32 + q * 8));
            f32x4 acc = {sh1v, sh1v, sh1v, sh1v};          // BN shift as C-init
            acc = __builtin_amdgcn_mfma_f32_16x16x32_bf16(a0, bw1[0], acc, 0, 0, 0);
            acc = __builtin_amdgcn_mfma_f32_16x16x32_bf16(a1, bw1[1], acc, 0, 0, 0);
            float s = fmaxf(acc[0], 0.f) + fmaxf(acc[1], 0.f) + fmaxf(acc[2], 0.f) + fmaxf(acc[3], 0.f);
            s += __shfl_xor(s, 16, 64);
            s += __shfl_xor(s, 32, 64);
            if (lane < 16) s_h1[mt * 72 + wave * 16 + lane] = f2bf(s);
        }
        __syncthreads();                                   // (c)

        // ---- GEMM2 (h1-sum) + skip GEMM (own feature), fused epilogue ----
        const unsigned short* h1row = s_h1 + c15 * 72;
        const unsigned short* forow = s_fo + c15 * 72;
        const bf16x8 ah0 = __builtin_bit_cast(bf16x8, *(const uint4*)(h1row + q * 8));
        const bf16x8 ah1 = __builtin_bit_cast(bf16x8, *(const uint4*)(h1row + 32 + q * 8));
        const bf16x8 af0 = __builtin_bit_cast(bf16x8, *(const uint4*)(forow + q * 8));
        const bf16x8 af1 = __builtin_bit_cast(bf16x8, *(const uint4*)(forow + 32 + q * 8));

#pragma unroll
        for (int nt = 0; nt < 2; ++nt) {
            f32x4 a2 = {sh2v[nt], sh2v[nt], sh2v[nt], sh2v[nt]};
            f32x4 a3 = {sh3v[nt], sh3v[nt], sh3v[nt], sh3v[nt]};
            a2 = __builtin_amdgcn_mfma_f32_16x16x32_bf16(ah0, bw2[nt][0], a2, 0, 0, 0);
            a2 = __builtin_amdgcn_mfma_f32_16x16x32_bf16(ah1, bw2[nt][1], a2, 0, 0, 0);
            a3 = __builtin_amdgcn_mfma_f32_16x16x32_bf16(af0, bw3[nt][0], a3, 0, 0, 0);
            a3 = __builtin_amdgcn_mfma_f32_16x16x32_bf16(af1, bw3[nt][1], a3, 0, 0, 0);
            const int d = wave * 32 + nt * 16 + c15;
#pragma unroll
            for (int r = 0; r < 4; ++r) {
                const int p = q * 4 + r;
                s_out[p * 132 + d] = fmaxf(a2[r], 0.f) + fmaxf(a3[r], 0.f);
            }
        }
        __syncthreads();                                   // (d)

        // ---- coalesced store: thread (2d+half) writes 32 B of row d ----
        {
            const int d = tid >> 1, half = tid & 1;
            float v[8];
#pragma unroll
            for (int i = 0; i < 8; ++i) v[i] = s_out[(half * 8 + i) * 132 + d];
            float* dst = out + ((size_t)b * Dd + d) * Nn + n0 + half * 8;
            *(f32x4*)dst = (f32x4){v[0], v[1], v[2], v[3]};
            *(f32x4*)(dst + 4) = (f32x4){v[4], v[5], v[6], v[7]};
        }
    }
}

extern "C" void kernel_launch(void* const* d_in, const int* in_sizes, int n_in,
                              void* d_out, int out_size, void* d_ws, size_t ws_size,
                              hipStream_t stream) {
    const float* feature = (const float*)d_in[0];
    const int*   neigh   = (const int*)d_in[1];
    const float* w1 = (const float*)d_in[2];
    const float* g1 = (const float*)d_in[3];
    const float* b1 = (const float*)d_in[4];
    const float* m1 = (const float*)d_in[5];
    const float* v1 = (const float*)d_in[6];
    const float* w2 = (const float*)d_in[7];
    const float* g2 = (const float*)d_in[8];
    const float* b2 = (const float*)d_in[9];
    const float* m2 = (const float*)d_in[10];
    const float* v2 = (const float*)d_in[11];
    const float* w3 = (const float*)d_in[12];
    const float* g3 = (const float*)d_in[13];
    const float* b3 = (const float*)d_in[14];
    const float* m3 = (const float*)d_in[15];
    const float* v3 = (const float*)d_in[16];
    float* out = (float*)d_out;

    char* ws = (char*)d_ws;
    unsigned short* ft  = (unsigned short*)ws;                    // 20,971,520 B
    unsigned short* w1s = (unsigned short*)(ws + 20971520);       //  8,192 B
    unsigned short* w2s = (unsigned short*)(ws + 20971520 + 8192);        // 16,384 B
    unsigned short* w3s = (unsigned short*)(ws + 20971520 + 24576);       // 16,384 B
    float* sh1 = (float*)(ws + 20971520 + 40960);                 // 256 B
    float* sh2 = (float*)(ws + 20971520 + 41216);                 // 512 B
    float* sh3 = (float*)(ws + 20971520 + 41728);                 // 512 B

    prep_weights<<<80, 256, 0, stream>>>(w1, g1, b1, m1, v1, w2, g2, b2, m2, v2,
                                         w3, g3, b3, m3, v3, w1s, w2s, w3s, sh1, sh2, sh3);
    transpose_cvt<<<Bb * (Nn / 64), 256, 0, stream>>>(feature, ft);
    fused_main<<<(Bb * TPB) / G, 256, 0, stream>>>(ft, neigh, w1s, w2s, w3s,
                                                   sh1, sh2, sh3, out);
}

// Round 3
// 308.560 us; speedup vs baseline: 1.0711x; 1.0711x over previous
//
#include <hip/hip_runtime.h>

#define EPSV 1e-5f
constexpr int Bb = 4, Cc = 64, Nn = 40960, Kk = 16, Dd = 128;
constexpr int G = 4;                       // point-tiles per block in fused_main
constexpr int TPB = Nn / 16;               // tiles per batch = 2560

typedef float f32x4 __attribute__((ext_vector_type(4)));
typedef __bf16 bf16x8 __attribute__((ext_vector_type(8)));
typedef unsigned short us8 __attribute__((ext_vector_type(8)));

__device__ inline unsigned short f2bf(float x) {
    unsigned u = __builtin_bit_cast(unsigned, x);
    u += 0x7FFFu + ((u >> 16) & 1u);   // RNE
    return (unsigned short)(u >> 16);
}

// ---------------------------------------------------------------------------
// Pass 1: feature (B,C,N) fp32 -> ft (B,N,C) bf16, LDS-tiled 64x64.
__global__ __launch_bounds__(256) void transpose_cvt(const float* __restrict__ f,
                                                     unsigned short* __restrict__ ft) {
    __shared__ float s[64 * 65];
    const int tid = threadIdx.x, w = tid >> 6, l = tid & 63;
    const int b = blockIdx.x / 640;
    const int n0 = (blockIdx.x % 640) * 64;

    const float* src = f + ((size_t)b * Cc + w * 16) * Nn + n0 + l;
#pragma unroll
    for (int i = 0; i < 16; ++i) s[(w * 16 + i) * 65 + l] = src[(size_t)i * Nn];
    __syncthreads();

    const int n = tid >> 2, cg = tid & 3;
    us8 o0, o1;
#pragma unroll
    for (int j = 0; j < 8; ++j) o0[j] = f2bf(s[(cg * 16 + j) * 65 + n]);
#pragma unroll
    for (int j = 0; j < 8; ++j) o1[j] = f2bf(s[(cg * 16 + 8 + j) * 65 + n]);
    unsigned short* dst = ft + ((size_t)b * Nn + n0 + n) * 64 + cg * 16;
    *(us8*)dst = o0;
    *(us8*)(dst + 8) = o1;
}

// ---------------------------------------------------------------------------
// Prep: fold BN scale into bf16 weights, precompute shifts.
__global__ __launch_bounds__(256) void prep_weights(
    const float* __restrict__ w1, const float* __restrict__ g1, const float* __restrict__ b1,
    const float* __restrict__ m1, const float* __restrict__ v1,
    const float* __restrict__ w2, const float* __restrict__ g2, const float* __restrict__ b2,
    const float* __restrict__ m2, const float* __restrict__ v2,
    const float* __restrict__ w3, const float* __restrict__ g3, const float* __restrict__ b3,
    const float* __restrict__ m3, const float* __restrict__ v3,
    unsigned short* __restrict__ w1s, unsigned short* __restrict__ w2s, unsigned short* __restrict__ w3s,
    float* __restrict__ sh1, float* __restrict__ sh2, float* __restrict__ sh3) {
    const int e = blockIdx.x * 256 + threadIdx.x;
    if (e < 4096) {
        const int o = e >> 6;
        const float sc = g1[o] * rsqrtf(v1[o] + EPSV);
        w1s[e] = f2bf(w1[e] * sc);
    } else if (e < 12288) {
        const int i = e - 4096, o = i >> 6;
        const float sc = g2[o] * rsqrtf(v2[o] + EPSV);
        w2s[i] = f2bf(w2[i] * sc);
    } else if (e < 20480) {
        const int i = e - 12288, o = i >> 6;
        const float sc = g3[o] * rsqrtf(v3[o] + EPSV);
        w3s[i] = f2bf(w3[i] * sc);
    }
    if (e < 64) sh1[e] = b1[e] - m1[e] * (g1[e] * rsqrtf(v1[e] + EPSV));
    else if (e < 192) { const int d = e - 64;  sh2[d] = b2[d] - m2[d] * (g2[d] * rsqrtf(v2[d] + EPSV)); }
    else if (e < 320) { const int d = e - 192; sh3[d] = b3[d] - m3[d] * (g3[d] * rsqrtf(v3[d] + EPSV)); }
}

// ---------------------------------------------------------------------------
// Main fused kernel: G point-tiles (16 points each) per block, 256 threads.
// Register-prefetch pipeline; __launch_bounds__(256,2) grants up to 256 VGPRs
// so the 8x uint4 prefetch + 10x bf16x8 weight frags stay in registers
// (round 2: default budget=76 VGPRs -> scratch spill -> 674 MB HBM traffic).
__global__ __launch_bounds__(256, 2) void fused_main(
    const unsigned short* __restrict__ ft, const int* __restrict__ idx,
    const unsigned short* __restrict__ w1s, const unsigned short* __restrict__ w2s,
    const unsigned short* __restrict__ w3s,
    const float* __restrict__ sh1, const float* __restrict__ sh2, const float* __restrict__ sh3,
    float* __restrict__ out) {
    __shared__ __attribute__((aligned(16))) unsigned short s_gath[256 * 72]; // 36 KB; s_out aliases
    __shared__ __attribute__((aligned(16))) unsigned short s_h1[16 * 72];
    __shared__ __attribute__((aligned(16))) unsigned short s_fo[16 * 72];
    float* s_out = (float*)s_gath;   // 16*132 floats, reused after GEMM1 reads done

    const int tid  = threadIdx.x;
    const int wave = tid >> 6;
    const int lane = tid & 63;
    const int c15  = lane & 15;
    const int q    = lane >> 4;
    const int sub  = lane & 7;
    const int rloc = lane >> 3;             // 0..7

    const int t0  = blockIdx.x * G;
    const int b   = t0 / TPB;               // G | TPB, so whole block is one batch
    const int nb0 = (t0 - b * TPB) * 16;

    // ---- register-resident weight fragments (pre-scaled bf16) ----
    const int o1i = wave * 16 + c15;
    const float sh1v = sh1[o1i];
    bf16x8 bw1[2];
#pragma unroll
    for (int ks = 0; ks < 2; ++ks)
        bw1[ks] = __builtin_bit_cast(bf16x8, *(const uint4*)(w1s + o1i * 64 + ks * 32 + q * 8));

    float sh2v[2], sh3v[2];
    bf16x8 bw2[2][2], bw3[2][2];
#pragma unroll
    for (int nt = 0; nt < 2; ++nt) {
        const int d = wave * 32 + nt * 16 + c15;
        sh2v[nt] = sh2[d];
        sh3v[nt] = sh3[d];
#pragma unroll
        for (int ks = 0; ks < 2; ++ks) {
            bw2[nt][ks] = __builtin_bit_cast(bf16x8, *(const uint4*)(w2s + d * 64 + ks * 32 + q * 8));
            bw3[nt][ks] = __builtin_bit_cast(bf16x8, *(const uint4*)(w3s + d * 64 + ks * 32 + q * 8));
        }
    }

    // ---- idx for all G tiles upfront (coalesced, 1 int/thread/tile) ----
    const size_t ibase = ((size_t)b * Nn + nb0) * Kk;
    int idxg[G];
#pragma unroll
    for (int g = 0; g < G; ++g) idxg[g] = idx[ibase + g * 256 + tid];

    const unsigned short* ftb = ft + (size_t)b * Nn * 64;

    uint4 preg[8];   // gather prefetch: rows 64*wave .. 64*wave+63, 16 B chunk `sub`
    uint4 freg;      // own-feature prefetch (threads < 128)

    // prefetch tile 0
#pragma unroll
    for (int i = 0; i < 8; ++i) {
        const int nb = __shfl(idxg[0], i * 8 + rloc, 64);
        preg[i] = *(const uint4*)(ftb + (size_t)nb * 64 + sub * 8);
    }
    if (tid < 128) freg = *(const uint4*)(ftb + (size_t)(nb0 + (tid >> 3)) * 64 + (tid & 7) * 8);

#pragma unroll
    for (int g = 0; g < G; ++g) {
        const int n0 = nb0 + g * 16;
        __syncthreads();                                   // (a) prev s_out reads done
#pragma unroll
        for (int i = 0; i < 8; ++i)
            *(uint4*)(s_gath + (64 * wave + i * 8 + rloc) * 72 + sub * 8) = preg[i];
        if (tid < 128)
            *(uint4*)(s_fo + (tid >> 3) * 72 + (tid & 7) * 8) = freg;
        __syncthreads();                                   // (b)

        // launch next tile's gather (overlaps all compute below)
        if (g + 1 < G) {
#pragma unroll
            for (int i = 0; i < 8; ++i) {
                const int nb = __shfl(idxg[g + 1], i * 8 + rloc, 64);
                preg[i] = *(const uint4*)(ftb + (size_t)nb * 64 + sub * 8);
            }
            if (tid < 128)
                freg = *(const uint4*)(ftb + (size_t)(n0 + 16 + (tid >> 3)) * 64 + (tid & 7) * 8);
        }

        // ---- GEMM1: per point, 16 nbrs x 64ch -> 16ch/wave; BN+ReLU; K-sum ----
#pragma unroll
        for (int mt = 0; mt < 16; ++mt) {
            const unsigned short* row = s_gath + (mt * 16 + c15) * 72;
            const bf16x8 a0 = __builtin_bit_cast(bf16x8, *(const uint4*)(row + q * 8));
            const bf16x8 a1 = __builtin_bit_cast(bf16x8, *(const uint4*)(row + 32 + q * 8));
            f32x4 acc = {sh1v, sh1v, sh1v, sh1v};          // BN shift as C-init
            acc = __builtin_amdgcn_mfma_f32_16x16x32_bf16(a0, bw1[0], acc, 0, 0, 0);
            acc = __builtin_amdgcn_mfma_f32_16x16x32_bf16(a1, bw1[1], acc, 0, 0, 0);
            float s = fmaxf(acc[0], 0.f) + fmaxf(acc[1], 0.f) + fmaxf(acc[2], 0.f) + fmaxf(acc[3], 0.f);
            s += __shfl_xor(s, 16, 64);
            s += __shfl_xor(s, 32, 64);
            if (lane < 16) s_h1[mt * 72 + wave * 16 + lane] = f2bf(s);
        }
        __syncthreads();                                   // (c)

        // ---- GEMM2 (h1-sum) + skip GEMM (own feature), fused epilogue ----
        const unsigned short* h1row = s_h1 + c15 * 72;
        const unsigned short* forow = s_fo + c15 * 72;
        const bf16x8 ah0 = __builtin_bit_cast(bf16x8, *(const uint4*)(h1row + q * 8));
        const bf16x8 ah1 = __builtin_bit_cast(bf16x8, *(const uint4*)(h1row + 32 + q * 8));
        const bf16x8 af0 = __builtin_bit_cast(bf16x8, *(const uint4*)(forow + q * 8));
        const bf16x8 af1 = __builtin_bit_cast(bf16x8, *(const uint4*)(forow + 32 + q * 8));

#pragma unroll
        for (int nt = 0; nt < 2; ++nt) {
            f32x4 a2 = {sh2v[nt], sh2v[nt], sh2v[nt], sh2v[nt]};
            f32x4 a3 = {sh3v[nt], sh3v[nt], sh3v[nt], sh3v[nt]};
            a2 = __builtin_amdgcn_mfma_f32_16x16x32_bf16(ah0, bw2[nt][0], a2, 0, 0, 0);
            a2 = __builtin_amdgcn_mfma_f32_16x16x32_bf16(ah1, bw2[nt][1], a2, 0, 0, 0);
            a3 = __builtin_amdgcn_mfma_f32_16x16x32_bf16(af0, bw3[nt][0], a3, 0, 0, 0);
            a3 = __builtin_amdgcn_mfma_f32_16x16x32_bf16(af1, bw3[nt][1], a3, 0, 0, 0);
            const int d = wave * 32 + nt * 16 + c15;
#pragma unroll
            for (int r = 0; r < 4; ++r) {
                const int p = q * 4 + r;
                s_out[p * 132 + d] = fmaxf(a2[r], 0.f) + fmaxf(a3[r], 0.f);
            }
        }
        __syncthreads();                                   // (d)

        // ---- coalesced nontemporal store: thread (2d+half) writes 32 B of row d ----
        {
            const int d = tid >> 1, half = tid & 1;
            float v[8];
#pragma unroll
            for (int i = 0; i < 8; ++i) v[i] = s_out[(half * 8 + i) * 132 + d];
            float* dst = out + ((size_t)b * Dd + d) * Nn + n0 + half * 8;
            __builtin_nontemporal_store((f32x4){v[0], v[1], v[2], v[3]}, (f32x4*)dst);
            __builtin_nontemporal_store((f32x4){v[4], v[5], v[6], v[7]}, (f32x4*)(dst + 4));
        }
    }
}

extern "C" void kernel_launch(void* const* d_in, const int* in_sizes, int n_in,
                              void* d_out, int out_size, void* d_ws, size_t ws_size,
                              hipStream_t stream) {
    const float* feature = (const float*)d_in[0];
    const int*   neigh   = (const int*)d_in[1];
    const float* w1 = (const float*)d_in[2];
    const float* g1 = (const float*)d_in[3];
    const float* b1 = (const float*)d_in[4];
    const float* m1 = (const float*)d_in[5];
    const float* v1 = (const float*)d_in[6];
    const float* w2 = (const float*)d_in[7];
    const float* g2 = (const float*)d_in[8];
    const float* b2 = (const float*)d_in[9];
    const float* m2 = (const float*)d_in[10];
    const float* v2 = (const float*)d_in[11];
    const float* w3 = (const float*)d_in[12];
    const float* g3 = (const float*)d_in[13];
    const float* b3 = (const float*)d_in[14];
    const float* m3 = (const float*)d_in[15];
    const float* v3 = (const float*)d_in[16];
    float* out = (float*)d_out;

    char* ws = (char*)d_ws;
    unsigned short* ft  = (unsigned short*)ws;                        // 20,971,520 B
    unsigned short* w1s = (unsigned short*)(ws + 20971520);           //  8,192 B
    unsigned short* w2s = (unsigned short*)(ws + 20971520 + 8192);    // 16,384 B
    unsigned short* w3s = (unsigned short*)(ws + 20971520 + 24576);   // 16,384 B
    float* sh1 = (float*)(ws + 20971520 + 40960);
    float* sh2 = (float*)(ws + 20971520 + 41216);
    float* sh3 = (float*)(ws + 20971520 + 41728);

    prep_weights<<<80, 256, 0, stream>>>(w1, g1, b1, m1, v1, w2, g2, b2, m2, v2,
                                         w3, g3, b3, m3, v3, w1s, w2s, w3s, sh1, sh2, sh3);
    transpose_cvt<<<Bb * (Nn / 64), 256, 0, stream>>>(feature, ft);
    fused_main<<<(Bb * TPB) / G, 256, 0, stream>>>(ft, neigh, w1s, w2s, w3s,
                                                   sh1, sh2, sh3, out);
}

// Round 4
// 227.819 us; speedup vs baseline: 1.4507x; 1.3544x over previous
//
#include <hip/hip_runtime.h>

#define EPSV 1e-5f
constexpr int Bb = 4, Cc = 64, Nn = 40960, Kk = 16, Dd = 128;
constexpr int G = 5;                       // point-tiles per block in pass B
constexpr int TPB = Nn / 16;               // tiles per batch = 2560

typedef float f32x4 __attribute__((ext_vector_type(4)));
typedef __bf16 bf16x8 __attribute__((ext_vector_type(8)));
typedef unsigned short us8 __attribute__((ext_vector_type(8)));
typedef unsigned short us4 __attribute__((ext_vector_type(4)));

__device__ inline unsigned short f2bf(float x) {
    unsigned u = __builtin_bit_cast(unsigned, x);
    u += 0x7FFFu + ((u >> 16) & 1u);   // RNE
    return (unsigned short)(u >> 16);
}

// ---------------------------------------------------------------------------
// Prep: fold BN scale into bf16 weights, precompute shifts.
__global__ __launch_bounds__(256) void prep_weights(
    const float* __restrict__ w1, const float* __restrict__ g1, const float* __restrict__ b1,
    const float* __restrict__ m1, const float* __restrict__ v1,
    const float* __restrict__ w2, const float* __restrict__ g2, const float* __restrict__ b2,
    const float* __restrict__ m2, const float* __restrict__ v2,
    const float* __restrict__ w3, const float* __restrict__ g3, const float* __restrict__ b3,
    const float* __restrict__ m3, const float* __restrict__ v3,
    unsigned short* __restrict__ w1s, unsigned short* __restrict__ w2s, unsigned short* __restrict__ w3s,
    float* __restrict__ sh1, float* __restrict__ sh2, float* __restrict__ sh3) {
    const int e = blockIdx.x * 256 + threadIdx.x;
    if (e < 4096) {
        const int o = e >> 6;
        const float sc = g1[o] * rsqrtf(v1[o] + EPSV);
        w1s[e] = f2bf(w1[e] * sc);
    } else if (e < 12288) {
        const int i = e - 4096, o = i >> 6;
        const float sc = g2[o] * rsqrtf(v2[o] + EPSV);
        w2s[i] = f2bf(w2[i] * sc);
    } else if (e < 20480) {
        const int i = e - 12288, o = i >> 6;
        const float sc = g3[o] * rsqrtf(v3[o] + EPSV);
        w3s[i] = f2bf(w3[i] * sc);
    }
    if (e < 64) sh1[e] = b1[e] - m1[e] * (g1[e] * rsqrtf(v1[e] + EPSV));
    else if (e < 192) { const int d = e - 64;  sh2[d] = b2[d] - m2[d] * (g2[d] * rsqrtf(v2[d] + EPSV)); }
    else if (e < 320) { const int d = e - 192; sh3[d] = b3[d] - m3[d] * (g3[d] * rsqrtf(v3[d] + EPSV)); }
}

// ---------------------------------------------------------------------------
// Pass A: G1 = sc1 * (W1 . f), stored (B,N,64) bf16. 64 points per block.
// LDS-transpose fp32 tile -> MFMA A-frags -> stage C-layout -> coalesced store.
__global__ __launch_bounds__(256) void passA(const float* __restrict__ f,
                                             const unsigned short* __restrict__ w1s,
                                             unsigned short* __restrict__ G1) {
    __shared__ float s[64 * 65];                            // [ch][pt]
    __shared__ __attribute__((aligned(16))) unsigned short sg1[64 * 72];  // [pt][ch]

    const int tid = threadIdx.x, w = tid >> 6, lane = tid & 63;
    const int c15 = lane & 15, q = lane >> 4;
    const int b = blockIdx.x / 640;
    const int n0 = (blockIdx.x % 640) * 64;

    // load fp32 tile: [64 ch][64 pts]
    const float* src = f + ((size_t)b * Cc + w * 16) * Nn + n0 + lane;
#pragma unroll
    for (int i = 0; i < 16; ++i) s[(w * 16 + i) * 65 + lane] = src[(size_t)i * Nn];

    // weight B-frags: out-channel o1 = w*16 + c15
    const int o1 = w * 16 + c15;
    bf16x8 bw1[2];
#pragma unroll
    for (int ks = 0; ks < 2; ++ks)
        bw1[ks] = __builtin_bit_cast(bf16x8, *(const uint4*)(w1s + o1 * 64 + ks * 32 + q * 8));
    __syncthreads();

#pragma unroll
    for (int mt = 0; mt < 4; ++mt) {
        const int pt = mt * 16 + c15;
        us8 A0, A1;
#pragma unroll
        for (int j = 0; j < 8; ++j) A0[j] = f2bf(s[(q * 8 + j) * 65 + pt]);
#pragma unroll
        for (int j = 0; j < 8; ++j) A1[j] = f2bf(s[(32 + q * 8 + j) * 65 + pt]);
        f32x4 g = {0.f, 0.f, 0.f, 0.f};
        g = __builtin_amdgcn_mfma_f32_16x16x32_bf16(__builtin_bit_cast(bf16x8, A0), bw1[0], g, 0, 0, 0);
        g = __builtin_amdgcn_mfma_f32_16x16x32_bf16(__builtin_bit_cast(bf16x8, A1), bw1[1], g, 0, 0, 0);
#pragma unroll
        for (int r = 0; r < 4; ++r) sg1[(mt * 16 + q * 4 + r) * 72 + o1] = f2bf(g[r]);
    }
    __syncthreads();

    // coalesced store: thread (p = tid>>2, ck = tid&3) writes 32 B of row p
    {
        const int p = tid >> 2, ck = tid & 3;
        const uint4 v0 = *(const uint4*)(sg1 + p * 72 + ck * 16);
        const uint4 v1 = *(const uint4*)(sg1 + p * 72 + ck * 16 + 8);
        unsigned short* dst = G1 + ((size_t)b * Nn + n0 + p) * 64 + ck * 16;
        *(uint4*)dst = v0;
        *(uint4*)(dst + 8) = v1;
    }
}

// ---------------------------------------------------------------------------
// Pass B: gather G1 rows directly from global (L2-resident), relu+sum -> h1;
// then W2.h1 + W3.f_own via MFMA, fused BN+ReLU epilogue, coalesced store.
__global__ __launch_bounds__(256, 4) void passB(
    const unsigned short* __restrict__ G1, const float* __restrict__ f,
    const int* __restrict__ idx,
    const unsigned short* __restrict__ w2s, const unsigned short* __restrict__ w3s,
    const float* __restrict__ sh1, const float* __restrict__ sh2, const float* __restrict__ sh3,
    float* __restrict__ out) {
    __shared__ __attribute__((aligned(16))) unsigned short s_h1[16 * 72];
    __shared__ float s_out[16 * 132];

    const int tid  = threadIdx.x;
    const int wave = tid >> 6;
    const int lane = tid & 63;
    const int c15  = lane & 15;
    const int q    = lane >> 4;
    const int pg   = tid >> 4;              // gather-phase point 0..15
    const int cg   = tid & 15;              // gather-phase channel group (4 ch)

    const int t0  = blockIdx.x * G;
    const int b   = t0 / TPB;               // 512 blocks per batch, G|TPB
    const int nb0 = (t0 - b * TPB) * 16;

    // weight B-frags (register-resident, bf16 pre-scaled)
    float sh2v[2], sh3v[2];
    bf16x8 bw2[2][2], bw3[2][2];
#pragma unroll
    for (int nt = 0; nt < 2; ++nt) {
        const int d = wave * 32 + nt * 16 + c15;
        sh2v[nt] = sh2[d];
        sh3v[nt] = sh3[d];
#pragma unroll
        for (int ks = 0; ks < 2; ++ks) {
            bw2[nt][ks] = __builtin_bit_cast(bf16x8, *(const uint4*)(w2s + d * 64 + ks * 32 + q * 8));
            bw3[nt][ks] = __builtin_bit_cast(bf16x8, *(const uint4*)(w3s + d * 64 + ks * 32 + q * 8));
        }
    }
    float shA[4];
#pragma unroll
    for (int j = 0; j < 4; ++j) shA[j] = sh1[cg * 4 + j];

    const unsigned short* G1b = G1 + (size_t)b * Nn * 64;
    const float* fb0 = f + (size_t)b * Cc * Nn;

    for (int g = 0; g < G; ++g) {
        const int n0 = nb0 + g * 16;

        // own-feature A-frags for the W3 skip path (strided fp32 -> bf16)
        const float* fown = fb0 + n0 + c15;
        us8 F0, F1;
#pragma unroll
        for (int j = 0; j < 8; ++j) F0[j] = f2bf(fown[(size_t)(q * 8 + j) * Nn]);
#pragma unroll
        for (int j = 0; j < 8; ++j) F1[j] = f2bf(fown[(size_t)(32 + q * 8 + j) * Nn]);

        // idx row `tid` of this tile (point pg, neighbor tid&15)
        const int myidx = idx[((size_t)b * Nn + n0) * Kk + tid];

        // gather + relu-sum: thread (pg, cg) accumulates 4 channels over 16 nbrs
        float a0 = 0.f, a1 = 0.f, a2 = 0.f, a3 = 0.f;
#pragma unroll
        for (int k = 0; k < 16; ++k) {
            const int nb = __shfl(myidx, (pg & 3) * 16 + k, 64);
            const uint2 d2 = *(const uint2*)(G1b + (size_t)nb * 64 + cg * 4);
            const float f0 = __builtin_bit_cast(float, d2.x << 16);
            const float f1 = __builtin_bit_cast(float, d2.x & 0xffff0000u);
            const float f2v = __builtin_bit_cast(float, d2.y << 16);
            const float f3 = __builtin_bit_cast(float, d2.y & 0xffff0000u);
            a0 += fmaxf(f0 + shA[0], 0.f);
            a1 += fmaxf(f1 + shA[1], 0.f);
            a2 += fmaxf(f2v + shA[2], 0.f);
            a3 += fmaxf(f3 + shA[3], 0.f);
        }

        __syncthreads();                     // prev iter's s_h1/s_out reads done
        us4 hv;
        hv[0] = f2bf(a0); hv[1] = f2bf(a1); hv[2] = f2bf(a2); hv[3] = f2bf(a3);
        *(us4*)(s_h1 + pg * 72 + cg * 4) = hv;
        __syncthreads();

        // GEMM2 (W2 . h1) + skip (W3 . f_own)
        const unsigned short* h1row = s_h1 + c15 * 72;
        const bf16x8 ah0 = __builtin_bit_cast(bf16x8, *(const uint4*)(h1row + q * 8));
        const bf16x8 ah1 = __builtin_bit_cast(bf16x8, *(const uint4*)(h1row + 32 + q * 8));
        const bf16x8 af0 = __builtin_bit_cast(bf16x8, F0);
        const bf16x8 af1 = __builtin_bit_cast(bf16x8, F1);

#pragma unroll
        for (int nt = 0; nt < 2; ++nt) {
            f32x4 h2 = {sh2v[nt], sh2v[nt], sh2v[nt], sh2v[nt]};
            f32x4 s3 = {sh3v[nt], sh3v[nt], sh3v[nt], sh3v[nt]};
            h2 = __builtin_amdgcn_mfma_f32_16x16x32_bf16(ah0, bw2[nt][0], h2, 0, 0, 0);
            h2 = __builtin_amdgcn_mfma_f32_16x16x32_bf16(ah1, bw2[nt][1], h2, 0, 0, 0);
            s3 = __builtin_amdgcn_mfma_f32_16x16x32_bf16(af0, bw3[nt][0], s3, 0, 0, 0);
            s3 = __builtin_amdgcn_mfma_f32_16x16x32_bf16(af1, bw3[nt][1], s3, 0, 0, 0);
            const int d = wave * 32 + nt * 16 + c15;
#pragma unroll
            for (int r = 0; r < 4; ++r) {
                const int p = q * 4 + r;
                s_out[p * 132 + d] = fmaxf(h2[r], 0.f) + fmaxf(s3[r], 0.f);
            }
        }
        __syncthreads();

        // coalesced nontemporal store: thread (2d+half) writes 32 B of row d
        {
            const int d = tid >> 1, half = tid & 1;
            float v[8];
#pragma unroll
            for (int i = 0; i < 8; ++i) v[i] = s_out[(half * 8 + i) * 132 + d];
            float* dst = out + ((size_t)b * Dd + d) * Nn + n0 + half * 8;
            __builtin_nontemporal_store((f32x4){v[0], v[1], v[2], v[3]}, (f32x4*)dst);
            __builtin_nontemporal_store((f32x4){v[4], v[5], v[6], v[7]}, (f32x4*)(dst + 4));
        }
    }
}

extern "C" void kernel_launch(void* const* d_in, const int* in_sizes, int n_in,
                              void* d_out, int out_size, void* d_ws, size_t ws_size,
                              hipStream_t stream) {
    const float* feature = (const float*)d_in[0];
    const int*   neigh   = (const int*)d_in[1];
    const float* w1 = (const float*)d_in[2];
    const float* g1 = (const float*)d_in[3];
    const float* b1 = (const float*)d_in[4];
    const float* m1 = (const float*)d_in[5];
    const float* v1 = (const float*)d_in[6];
    const float* w2 = (const float*)d_in[7];
    const float* g2 = (const float*)d_in[8];
    const float* b2 = (const float*)d_in[9];
    const float* m2 = (const float*)d_in[10];
    const float* v2 = (const float*)d_in[11];
    const float* w3 = (const float*)d_in[12];
    const float* g3 = (const float*)d_in[13];
    const float* b3 = (const float*)d_in[14];
    const float* m3 = (const float*)d_in[15];
    const float* v3 = (const float*)d_in[16];
    float* out = (float*)d_out;

    char* ws = (char*)d_ws;
    unsigned short* G1  = (unsigned short*)ws;                        // 20,971,520 B
    unsigned short* w1s = (unsigned short*)(ws + 20971520);           //  8,192 B
    unsigned short* w2s = (unsigned short*)(ws + 20971520 + 8192);    // 16,384 B
    unsigned short* w3s = (unsigned short*)(ws + 20971520 + 24576);   // 16,384 B
    float* sh1 = (float*)(ws + 20971520 + 40960);
    float* sh2 = (float*)(ws + 20971520 + 41216);
    float* sh3 = (float*)(ws + 20971520 + 41728);

    prep_weights<<<80, 256, 0, stream>>>(w1, g1, b1, m1, v1, w2, g2, b2, m2, v2,
                                         w3, g3, b3, m3, v3, w1s, w2s, w3s, sh1, sh2, sh3);
    passA<<<Bb * 640, 256, 0, stream>>>(feature, w1s, G1);
    passB<<<(Bb * TPB) / G, 256, 0, stream>>>(G1, feature, neigh, w2s, w3s,
                                              sh1, sh2, sh3, out);
}